// Round 4
// baseline (345.670 us; speedup 1.0000x reference)
//
#include <hip/hip_runtime.h>
#include <stdint.h>

// Fully-fused: bilinear 1024->256 (exact 2x2 avg) + reflect-pad 30 + 127-tap
// separable Gaussian (zero-padded conv on 316x316) + crop, in ONE kernel.
// Grid = (4 x-strips of 64 out cols) x (48 channel-images), 512 threads.
//
// Phase 1 (per wave, no cross-wave deps): for each 4-row quad of the 316
//   padded rows: resize 192 cols (the 64-col strip + 63/65 halo) into a
//   wave-private fp16 Rext buffer, then horizontal 127-tap blur via the
//   zero-padded sliding-float4 weight trick; store fp16 into LDS strip
//   Hs[384][68] (rows offset +33; rows [0,33) & [349,384) stay zero ->
//   vertical conv is branch-free; stride 68 halfs -> conflict-light).
// Phase 2: vertical 127-tap blur reading Hs, fp32 accumulate, float4 store.
//
// LDS: W4 544 + partial 32 + Rext 8*4*192*2=12288 + Hs 384*68*2=52224
//    = 65088 B <= 64 KiB static limit.

#define CHTOT 48
#define IN_W  1024
#define OUT_W 256
#define PADW  316
#define KTAP  127

typedef _Float16 half_t;
typedef __attribute__((ext_vector_type(4))) _Float16 half4;

__device__ __forceinline__ float4 f4fma(float4 v, float w, float4 a) {
    a.x = fmaf(v.x, w, a.x); a.y = fmaf(v.y, w, a.y);
    a.z = fmaf(v.z, w, a.z); a.w = fmaf(v.w, w, a.w);
    return a;
}
__device__ __forceinline__ float4 h2f4(half4 h) {
    return make_float4((float)h.x, (float)h.y, (float)h.z, (float)h.w);
}

__global__ __launch_bounds__(512) void fused_kernel(const float* __restrict__ in,
                                                    float* __restrict__ out) {
    __shared__ float4 W4[34];            // 136 floats, zero padded: W[3+t]=g[t]
    __shared__ float  partial[8];
    __shared__ half_t Rext[8][4][192];   // wave-private resize buffers
    __shared__ half_t Hs[384 * 68];      // H strip, row p at Hs[(33+p)*68]

    const int tid  = threadIdx.x;
    const int w    = tid >> 6;
    const int lane = tid & 63;
    float* W = (float*)W4;

    // ---- weights (parallel reduction) + zero Hs ----
    {
        float e = 0.f;
        if (tid < KTAP) {
            float q = (float)(tid - 63) * (1.0f / 21.0f);
            e = exp2f(-q * q);
        }
        float s = e;
        #pragma unroll
        for (int off = 32; off >= 1; off >>= 1) s += __shfl_down(s, off, 64);
        if (lane == 0) partial[w] = s;
        if (tid < 34) W4[tid] = make_float4(0.f, 0.f, 0.f, 0.f);
        for (int i = tid; i < 384 * 68 / 2; i += 512) ((unsigned int*)Hs)[i] = 0u;
        __syncthreads();
        float S = 0.f;
        #pragma unroll
        for (int k = 0; k < 8; ++k) S += partial[k];
        if (tid < KTAP) W[3 + tid] = e / S;
        __syncthreads();
    }

    const int X0 = blockIdx.x * 64;                       // strip's first out col
    const size_t chbase = (size_t)blockIdx.y * (IN_W * IN_W);
    const float4* in4 = (const float4*)(in + chbase);

    // ---- phase 1: resize + horizontal blur, 4-row quads per wave ----
    for (int it = 0; it < 10; ++it) {
        int quad = it * 8 + w;                            // 0..79 (79 valid)
        bool active = quad < 79;
        if (active) {
            int p_base = quad * 4;
            #pragma unroll
            for (int k = 0; k < 12; ++k) {
                int s = k * 64 + lane;                    // 0..767
                int rr = s / 192;
                int c  = s - rr * 192;
                int q  = X0 - 33 + c;                     // padded col
                float val = 0.f;
                if (q >= 0 && q < PADW) {
                    int yq = q - 30;
                    int xr = yq < 0 ? -yq : (yq > 255 ? 510 - yq : yq);
                    int pp = p_base + rr - 30;
                    int r  = pp < 0 ? -pp : (pp > 255 ? 510 - pp : pp);
                    float4 a = in4[(4 * r + 1) * (IN_W / 4) + xr];
                    float4 b = in4[(4 * r + 2) * (IN_W / 4) + xr];
                    float m1 = 0.5f * a.y + 0.5f * b.y;   // axis2 first
                    float m2 = 0.5f * a.z + 0.5f * b.z;
                    val = 0.5f * m1 + 0.5f * m2;          // then axis3
                }
                Rext[w][rr][c] = (half_t)val;
            }
        }
        __syncthreads();                                  // uniform; orders fill->read
        if (active) {
            int rr = lane >> 4, u = lane & 15;            // row-in-quad, col-group
            const half4* Rv = (const half4*)(&Rext[w][rr][0]);
            float acc0 = 0.f, acc1 = 0.f, acc2 = 0.f, acc3 = 0.f;
            float4 wlo = W4[0];
            #pragma unroll
            for (int i = 0; i < 33; ++i) {
                float4 whi = W4[i + 1];
                half4 h = Rv[u + i];                      // c = 4u+4i..+3, max 47
                float vx = (float)h.x, vy = (float)h.y, vz = (float)h.z, vw = (float)h.w;
                acc0 = fmaf(vx, wlo.w, acc0); acc0 = fmaf(vy, whi.x, acc0);
                acc0 = fmaf(vz, whi.y, acc0); acc0 = fmaf(vw, whi.z, acc0);
                acc1 = fmaf(vx, wlo.z, acc1); acc1 = fmaf(vy, wlo.w, acc1);
                acc1 = fmaf(vz, whi.x, acc1); acc1 = fmaf(vw, whi.y, acc1);
                acc2 = fmaf(vx, wlo.y, acc2); acc2 = fmaf(vy, wlo.z, acc2);
                acc2 = fmaf(vz, wlo.w, acc2); acc2 = fmaf(vw, whi.x, acc2);
                acc3 = fmaf(vx, wlo.x, acc3); acc3 = fmaf(vy, wlo.y, acc3);
                acc3 = fmaf(vz, wlo.z, acc3); acc3 = fmaf(vw, wlo.w, acc3);
                wlo = whi;
            }
            int p = quad * 4 + rr;                        // padded row 0..315
            half4 hv;
            hv.x = (half_t)acc0; hv.y = (half_t)acc1;
            hv.z = (half_t)acc2; hv.w = (half_t)acc3;
            *(half4*)(&Hs[(33 + p) * 68 + 4 * u]) = hv;
        }
    }
    __syncthreads();                                      // Hs complete

    // ---- phase 2: vertical blur from LDS, 2 passes of 128 out rows ----
    const int cg = tid & 15;                              // half4 col group
    float4* out4 = (float4*)out;
    #pragma unroll
    for (int ph = 0; ph < 2; ++ph) {
        int gl = ph * 32 + (tid >> 4);                    // 0..63 -> rows 4gl..+3
        float4 acc0 = make_float4(0,0,0,0), acc1 = acc0, acc2 = acc0, acc3 = acc0;
        float4 wlo = W4[0];
        #pragma unroll
        for (int i = 0; i < 33; ++i) {
            float4 whi = W4[i + 1];
            int base = (4 * gl + 4 * i) * 68 + 4 * cg;    // Hs idx, max row 383
            float4 v0 = h2f4(*(const half4*)(&Hs[base]));
            float4 v1 = h2f4(*(const half4*)(&Hs[base + 68]));
            float4 v2 = h2f4(*(const half4*)(&Hs[base + 136]));
            float4 v3 = h2f4(*(const half4*)(&Hs[base + 204]));
            acc0 = f4fma(v0, wlo.w, acc0); acc0 = f4fma(v1, whi.x, acc0);
            acc0 = f4fma(v2, whi.y, acc0); acc0 = f4fma(v3, whi.z, acc0);
            acc1 = f4fma(v0, wlo.z, acc1); acc1 = f4fma(v1, wlo.w, acc1);
            acc1 = f4fma(v2, whi.x, acc1); acc1 = f4fma(v3, whi.y, acc1);
            acc2 = f4fma(v0, wlo.y, acc2); acc2 = f4fma(v1, wlo.z, acc2);
            acc2 = f4fma(v2, wlo.w, acc2); acc2 = f4fma(v3, whi.x, acc2);
            acc3 = f4fma(v0, wlo.x, acc3); acc3 = f4fma(v1, wlo.y, acc3);
            acc3 = f4fma(v2, wlo.z, acc3); acc3 = f4fma(v3, wlo.w, acc3);
            wlo = whi;
        }
        float4 accs[4] = {acc0, acc1, acc2, acc3};
        #pragma unroll
        for (int j = 0; j < 4; ++j) {
            int y = 4 * gl + j;
            out4[((size_t)blockIdx.y * OUT_W + y) * 64 + blockIdx.x * 16 + cg] = accs[j];
        }
    }
}

extern "C" void kernel_launch(void* const* d_in, const int* in_sizes, int n_in,
                              void* d_out, int out_size, void* d_ws, size_t ws_size,
                              hipStream_t stream) {
    const float* in = (const float*)d_in[0];
    float* out = (float*)d_out;
    fused_kernel<<<dim3(4, CHTOT), dim3(512), 0, stream>>>(in, out);
}

// Round 5
// 310.372 us; speedup vs baseline: 1.1137x; 1.1137x over previous
//
#include <hip/hip_runtime.h>
#include <stdint.h>

// Preprocess: bilinear 1024->256 (exact 2x2 avg) + reflect-pad 30 + 127-tap
// separable Gaussian (zero-padded conv on 316x316) + crop. fp32 in/out.
//
// R5 structure (reverted from R4's failed mega-fusion, which bottomed at
// 1 block/CU): K0 precomputes weights to ws; K1 = resize + h-blur (8 rows
// per block, 1920 blocks); K2 = v-blur from fp16 H (768 blocks). Per-block
// weight preamble (exp2f + shuffle chain + 2 barriers) eliminated.

#define CHTOT 48
#define IN_W  1024
#define OUT_W 256
#define PADW  316
#define KTAP  127

typedef _Float16 half_t;
typedef __attribute__((ext_vector_type(4))) _Float16 half4;

__device__ __forceinline__ float4 f4fma(float4 v, float w, float4 a) {
    a.x = fmaf(v.x, w, a.x); a.y = fmaf(v.y, w, a.y);
    a.z = fmaf(v.z, w, a.z); a.w = fmaf(v.w, w, a.w);
    return a;
}
__device__ __forceinline__ float4 h2f4(half4 h) {
    return make_float4((float)h.x, (float)h.y, (float)h.z, (float)h.w);
}

// K0: Wg[136] = {0,0,0, g[0..127), 0..0}, normalized. One block.
__global__ __launch_bounds__(256) void weights_kernel(float* __restrict__ Wg) {
    __shared__ float partial[4];
    int tid = threadIdx.x;
    float e = 0.f;
    if (tid < KTAP) {
        float q = (float)(tid - 63) * (1.0f / 21.0f);
        e = exp2f(-q * q);
    }
    float s = e;
    #pragma unroll
    for (int off = 32; off >= 1; off >>= 1) s += __shfl_down(s, off, 64);
    if ((tid & 63) == 0) partial[tid >> 6] = s;
    __syncthreads();
    float S = partial[0] + partial[1] + partial[2] + partial[3];
    if (tid < 136) {
        int t = tid - 3;
        float v = 0.f;
        if (t >= 0 && t < KTAP) {
            float q = (float)(t - 63) * (1.0f / 21.0f);
            v = exp2f(-q * q) / S;
        }
        Wg[tid] = v;
    }
}

// K1: 8 padded rows per block. Stage+resize into Rext[8][384] (borders:
// zeros + reflect), then 127-tap h-blur (zero-padded sliding float4
// weights, branch-free), store fp16 H row strips.
__global__ __launch_bounds__(256) void hblur_kernel(const float* __restrict__ in,
                                                    const float* __restrict__ Wg,
                                                    half_t* __restrict__ H) {
    __shared__ float4 W4[34];
    __shared__ float Rext[8][384];
    int tid = threadIdx.x;
    if (tid < 34) W4[tid] = ((const float4*)Wg)[tid];

    int ch = blockIdx.y;
    int p0 = blockIdx.x * 8;                 // 40*8=320, rows >=316 discarded
    const float4* in4 = (const float4*)(in + (size_t)ch * (IN_W * IN_W));

    // ---- stage + resize: one 256-wide row per pass ----
    int j = tid;                             // 0..255
    #pragma unroll
    for (int rr = 0; rr < 8; ++rr) {
        int pp = p0 + rr - 30;
        int r = pp < 0 ? -pp : (pp > 255 ? 510 - pp : pp);   // reflect rows
        float4 a = in4[(4 * r + 1) * (IN_W / 4) + j];
        float4 b = in4[(4 * r + 2) * (IN_W / 4) + j];
        float m1 = 0.5f * a.y + 0.5f * b.y;  // axis2 (rows) first
        float m2 = 0.5f * a.z + 0.5f * b.z;
        Rext[rr][63 + j] = 0.5f * m1 + 0.5f * m2;            // then axis3
    }
    __syncthreads();

    // ---- borders: 128 slots/row, 2 rows per pass ----
    {
        int s = tid & 127;
        int rbase = tid >> 7;                // 0..1
        #pragma unroll
        for (int pass = 0; pass < 4; ++pass) {
            float* Rx = Rext[pass * 2 + rbase];
            if (s < 33)      Rx[s] = 0.f;                    // zeros left
            else if (s < 63) Rx[s] = Rx[126 - s];            // reflect left
            else if (s < 93) Rx[s + 256] = Rx[380 - s];      // reflect right
            else             Rx[s + 256] = 0.f;              // zeros right
        }
    }
    __syncthreads();

    // ---- h-blur: wave g handles rows g and g+4 ----
    int g = tid >> 6;
    int l = tid & 63;
    for (int h = 0; h < 2; ++h) {
        int rp = g + h * 4;
        int p = p0 + rp;
        const float4* Rv = (const float4*)Rext[rp];
        float acc0 = 0.f, acc1 = 0.f, acc2 = 0.f, acc3 = 0.f;
        float4 wlo = W4[0];
        #pragma unroll
        for (int i = 0; i < 33; ++i) {
            float4 whi = W4[i + 1];
            float4 v = Rv[l + i];
            acc0 = fmaf(v.x, wlo.w, acc0); acc0 = fmaf(v.y, whi.x, acc0);
            acc0 = fmaf(v.z, whi.y, acc0); acc0 = fmaf(v.w, whi.z, acc0);
            acc1 = fmaf(v.x, wlo.z, acc1); acc1 = fmaf(v.y, wlo.w, acc1);
            acc1 = fmaf(v.z, whi.x, acc1); acc1 = fmaf(v.w, whi.y, acc1);
            acc2 = fmaf(v.x, wlo.y, acc2); acc2 = fmaf(v.y, wlo.z, acc2);
            acc2 = fmaf(v.z, wlo.w, acc2); acc2 = fmaf(v.w, whi.x, acc2);
            acc3 = fmaf(v.x, wlo.x, acc3); acc3 = fmaf(v.y, wlo.y, acc3);
            acc3 = fmaf(v.z, wlo.z, acc3); acc3 = fmaf(v.w, wlo.w, acc3);
            wlo = whi;
        }
        if (p < PADW) {
            half4 hv;
            hv.x = (half_t)acc0; hv.y = (half_t)acc1;
            hv.z = (half_t)acc2; hv.w = (half_t)acc3;
            ((half4*)H)[((size_t)ch * PADW + p) * 64 + l] = hv;
        }
    }
}

// K2: 64x64 output tile; stage 192x64 fp16 H strip -> fp32 LDS; v-blur.
__global__ __launch_bounds__(256) void vblur_kernel(const half_t* __restrict__ H,
                                                    const float* __restrict__ Wg,
                                                    float* __restrict__ out) {
    __shared__ float4 W4[34];
    __shared__ float4 T[192 * 16];           // 192 rows x 64 fp32 cols (48 KB)
    int tid = threadIdx.x;
    if (tid < 34) W4[tid] = ((const float4*)Wg)[tid];

    int ch = blockIdx.y;
    int xt = blockIdx.x & 3;
    int yt = blockIdx.x >> 2;
    int x0h4 = xt * 16;
    int y0 = yt * 64;

    const half4* H4 = (const half4*)H;
    for (int idx = tid; idx < 192 * 16; idx += 256) {
        int rr = idx >> 4, fx = idx & 15;
        int r = y0 - 33 + rr;                // zero outside [0,316)
        float4 v = make_float4(0.f, 0.f, 0.f, 0.f);
        if (r >= 0 && r < PADW) v = h2f4(H4[((size_t)ch * PADW + r) * 64 + x0h4 + fx]);
        T[idx] = v;
    }
    __syncthreads();

    int cg = tid & 15;
    int g  = tid >> 4;                       // output rows 4g..4g+3
    float4 acc0 = make_float4(0,0,0,0), acc1 = acc0, acc2 = acc0, acc3 = acc0;
    float4 wlo = W4[0];
    #pragma unroll
    for (int i = 0; i < 33; ++i) {
        float4 whi = W4[i + 1];
        int base = (4 * g + 4 * i) * 16 + cg;
        float4 v0 = T[base];
        float4 v1 = T[base + 16];
        float4 v2 = T[base + 32];
        float4 v3 = T[base + 48];
        acc0 = f4fma(v0, wlo.w, acc0); acc0 = f4fma(v1, whi.x, acc0);
        acc0 = f4fma(v2, whi.y, acc0); acc0 = f4fma(v3, whi.z, acc0);
        acc1 = f4fma(v0, wlo.z, acc1); acc1 = f4fma(v1, wlo.w, acc1);
        acc1 = f4fma(v2, whi.x, acc1); acc1 = f4fma(v3, whi.y, acc1);
        acc2 = f4fma(v0, wlo.y, acc2); acc2 = f4fma(v1, wlo.z, acc2);
        acc2 = f4fma(v2, wlo.w, acc2); acc2 = f4fma(v3, whi.x, acc2);
        acc3 = f4fma(v0, wlo.x, acc3); acc3 = f4fma(v1, wlo.y, acc3);
        acc3 = f4fma(v2, wlo.z, acc3); acc3 = f4fma(v3, wlo.w, acc3);
        wlo = whi;
    }

    float4* o4 = (float4*)out;
    float4 accs[4] = {acc0, acc1, acc2, acc3};
    #pragma unroll
    for (int j = 0; j < 4; ++j) {
        int y = y0 + 4 * g + j;
        o4[((size_t)ch * OUT_W + y) * 64 + xt * 16 + cg] = accs[j];
    }
}

extern "C" void kernel_launch(void* const* d_in, const int* in_sizes, int n_in,
                              void* d_out, int out_size, void* d_ws, size_t ws_size,
                              hipStream_t stream) {
    const float* in = (const float*)d_in[0];
    float* out = (float*)d_out;
    float* Wg = (float*)d_ws;                         // 136 floats
    half_t* H = (half_t*)((char*)d_ws + 1024);        // 48*316*256 fp16 = 7.8 MB

    weights_kernel<<<dim3(1), dim3(256), 0, stream>>>(Wg);
    hblur_kernel<<<dim3(40, CHTOT), dim3(256), 0, stream>>>(in, Wg, H);
    vblur_kernel<<<dim3(16, CHTOT), dim3(256), 0, stream>>>(H, Wg, out);
}

// Round 6
// 263.363 us; speedup vs baseline: 1.3125x; 1.1785x over previous
//
#include <hip/hip_runtime.h>
#include <stdint.h>

// Preprocess: bilinear 1024->256 (exact 2x2 avg since scale=4) + reflect-pad
// 30 + 127-tap separable Gaussian (zero-padded conv on 316x316) + crop.
// fp32 in/out. fp16 H intermediate in ws.
//
// R6: K1 is wave-autonomous (ZERO barriers): each wave owns one padded row:
//   load 2 input rows (coalesced) -> resize -> wave-private LDS row (zeros +
//   reflect borders, in-order DS pipe, no sync) -> 127-tap h-blur (zero-padded
//   sliding float4 weights) -> fp16 store. Weights per-wave with analytic
//   normalizer 1/S (S = 44.69106, exact to ~1e-4 rel; output effect ~1e-5).
// K2: 64x64 tile v-blur (1 barrier for the tile), same per-wave weights.

#define CHTOT 48
#define IN_W  1024
#define OUT_W 256
#define PADW  316
#define KTAP  127
#define INV_S 0.02237584f   // 1 / sum_{x=-63..63} 2^(-(x/21)^2)

typedef _Float16 half_t;
typedef __attribute__((ext_vector_type(4))) _Float16 half4;

__device__ __forceinline__ float4 f4fma(float4 v, float w, float4 a) {
    a.x = fmaf(v.x, w, a.x); a.y = fmaf(v.y, w, a.y);
    a.z = fmaf(v.z, w, a.z); a.w = fmaf(v.w, w, a.w);
    return a;
}
__device__ __forceinline__ float4 h2f4(half4 h) {
    return make_float4((float)h.x, (float)h.y, (float)h.z, (float)h.w);
}

// Fill this wave's 136-slot zero-padded normalized weight row. No barrier.
__device__ __forceinline__ void wave_weights(float* W, int l) {
    float q0 = (float)(l - 63) * (1.0f / 21.0f);          // t = l (3..66)
    W[3 + l] = exp2f(-q0 * q0) * INV_S;
    if (l < 63) {                                          // t = l+64 (67..129)
        float q1 = (float)(l + 1) * (1.0f / 21.0f);
        W[67 + l] = exp2f(-q1 * q1) * INV_S;
    }
    if (l < 3) W[l] = 0.f;                                 // slots 0..2
    if (l >= 58) W[72 + l] = 0.f;                          // slots 130..135
}

__global__ __launch_bounds__(256) void hblur_kernel(const float* __restrict__ in,
                                                    half_t* __restrict__ H) {
    __shared__ float Wp[4][136];     // per-wave weights (544 B each, 16B-aligned)
    __shared__ float Rw[4][384];     // per-wave extended row
    const int tid = threadIdx.x;
    const int w = tid >> 6, l = tid & 63;
    float* W = Wp[w];
    wave_weights(W, l);

    const int ch = blockIdx.y;
    const int p = blockIdx.x * 4 + w;            // padded row 0..315 (79*4=316)
    const float4* in4 = (const float4*)(in + (size_t)ch * (IN_W * IN_W));

    // ---- resize this row: cols l, l+64, l+128, l+192 ----
    int pp = p - 30;
    int r = pp < 0 ? -pp : (pp > 255 ? 510 - pp : pp);     // reflect rows
    const float4* row1 = in4 + (4 * r + 1) * (IN_W / 4);
    const float4* row2 = row1 + (IN_W / 4);
    float* Rx = Rw[w];
    #pragma unroll
    for (int k = 0; k < 4; ++k) {
        float4 a = row1[l + 64 * k];
        float4 b = row2[l + 64 * k];
        float m1 = 0.5f * a.y + 0.5f * b.y;                // axis2 (rows) first
        float m2 = 0.5f * a.z + 0.5f * b.z;
        Rx[63 + l + 64 * k] = 0.5f * m1 + 0.5f * m2;       // then axis3
    }
    // ---- borders (within-wave; DS pipe is in-order, no barrier) ----
    if (l < 33)      Rx[l] = 0.f;                          // left zeros 0..32
    else if (l < 63) Rx[l] = Rx[126 - l];                  // left mirror 33..62
    {
        int e = 319 + l;                                   // 319..382
        float v = (e < 349) ? Rx[636 - e] : 0.f;           // right mirror/zeros
        Rx[e] = v;
        if (l == 63) Rx[383] = 0.f;
    }

    // ---- 127-tap h-blur: out cols 4l..4l+3 ----
    const float4* Rv = (const float4*)Rx;
    const float4* W4 = (const float4*)W;
    float acc0 = 0.f, acc1 = 0.f, acc2 = 0.f, acc3 = 0.f;
    float4 wlo = W4[0];
    #pragma unroll
    for (int i = 0; i < 33; ++i) {
        float4 whi = W4[i + 1];
        float4 v = Rv[l + i];
        acc0 = fmaf(v.x, wlo.w, acc0); acc0 = fmaf(v.y, whi.x, acc0);
        acc0 = fmaf(v.z, whi.y, acc0); acc0 = fmaf(v.w, whi.z, acc0);
        acc1 = fmaf(v.x, wlo.z, acc1); acc1 = fmaf(v.y, wlo.w, acc1);
        acc1 = fmaf(v.z, whi.x, acc1); acc1 = fmaf(v.w, whi.y, acc1);
        acc2 = fmaf(v.x, wlo.y, acc2); acc2 = fmaf(v.y, wlo.z, acc2);
        acc2 = fmaf(v.z, wlo.w, acc2); acc2 = fmaf(v.w, whi.x, acc2);
        acc3 = fmaf(v.x, wlo.x, acc3); acc3 = fmaf(v.y, wlo.y, acc3);
        acc3 = fmaf(v.z, wlo.z, acc3); acc3 = fmaf(v.w, wlo.w, acc3);
        wlo = whi;
    }
    half4 hv;
    hv.x = (half_t)acc0; hv.y = (half_t)acc1;
    hv.z = (half_t)acc2; hv.w = (half_t)acc3;
    ((half4*)H)[((size_t)ch * PADW + p) * 64 + l] = hv;
}

__global__ __launch_bounds__(256) void vblur_kernel(const half_t* __restrict__ H,
                                                    float* __restrict__ out) {
    __shared__ float  Wp[4][136];
    __shared__ float4 T[192 * 16];               // 192 rows x 64 fp32 cols
    const int tid = threadIdx.x;
    const int w = tid >> 6, l = tid & 63;
    wave_weights(Wp[w], l);

    const int ch = blockIdx.y;
    const int xt = blockIdx.x & 3;
    const int yt = blockIdx.x >> 2;
    const int x0h4 = xt * 16;
    const int y0 = yt * 64;

    const half4* H4 = (const half4*)H;
    for (int idx = tid; idx < 192 * 16; idx += 256) {
        int rr = idx >> 4, fx = idx & 15;
        int r = y0 - 33 + rr;                    // zero outside [0,316)
        float4 v = make_float4(0.f, 0.f, 0.f, 0.f);
        if (r >= 0 && r < PADW) v = h2f4(H4[((size_t)ch * PADW + r) * 64 + x0h4 + fx]);
        T[idx] = v;
    }
    __syncthreads();

    const float4* W4 = (const float4*)Wp[w];
    int cg = tid & 15;
    int g  = tid >> 4;                           // output rows 4g..4g+3
    float4 acc0 = make_float4(0,0,0,0), acc1 = acc0, acc2 = acc0, acc3 = acc0;
    float4 wlo = W4[0];
    #pragma unroll
    for (int i = 0; i < 33; ++i) {
        float4 whi = W4[i + 1];
        int base = (4 * g + 4 * i) * 16 + cg;    // max T row 191
        float4 v0 = T[base];
        float4 v1 = T[base + 16];
        float4 v2 = T[base + 32];
        float4 v3 = T[base + 48];
        acc0 = f4fma(v0, wlo.w, acc0); acc0 = f4fma(v1, whi.x, acc0);
        acc0 = f4fma(v2, whi.y, acc0); acc0 = f4fma(v3, whi.z, acc0);
        acc1 = f4fma(v0, wlo.z, acc1); acc1 = f4fma(v1, wlo.w, acc1);
        acc1 = f4fma(v2, whi.x, acc1); acc1 = f4fma(v3, whi.y, acc1);
        acc2 = f4fma(v0, wlo.y, acc2); acc2 = f4fma(v1, wlo.z, acc2);
        acc2 = f4fma(v2, wlo.w, acc2); acc2 = f4fma(v3, whi.x, acc2);
        acc3 = f4fma(v0, wlo.x, acc3); acc3 = f4fma(v1, wlo.y, acc3);
        acc3 = f4fma(v2, wlo.z, acc3); acc3 = f4fma(v3, wlo.w, acc3);
        wlo = whi;
    }

    float4* o4 = (float4*)out;
    float4 accs[4] = {acc0, acc1, acc2, acc3};
    #pragma unroll
    for (int j = 0; j < 4; ++j) {
        int y = y0 + 4 * g + j;
        o4[((size_t)ch * OUT_W + y) * 64 + xt * 16 + cg] = accs[j];
    }
}

extern "C" void kernel_launch(void* const* d_in, const int* in_sizes, int n_in,
                              void* d_out, int out_size, void* d_ws, size_t ws_size,
                              hipStream_t stream) {
    const float* in = (const float*)d_in[0];
    float* out = (float*)d_out;
    half_t* H = (half_t*)d_ws;                   // 48*316*256 fp16 = 7.8 MB

    hblur_kernel<<<dim3(79, CHTOT), dim3(256), 0, stream>>>(in, H);
    vblur_kernel<<<dim3(16, CHTOT), dim3(256), 0, stream>>>(H, out);
}